// Round 14
// baseline (484.203 us; speedup 1.0000x reference)
//
#include <hip/hip_runtime.h>
#include <math.h>

#define BB 4
#define HH 16
#define SS 8192
#define HDD 64
#define DD 1024
#define MEM 65536
#define KT 10
#define AUGROWS (SS + KT)

// ---------------- output offsets (floats) ----------------
static const long O0 = 0;          // inputs      33554432
static const long O1 = 33554432;   // q           33554432
static const long O2 = 67108864;   // aug_k       33595392 (B,H,S+KT,HD)
static const long O3 = 100704256;  // aug_v       33595392
static const long O4 = 134299648;  // aug_mask    32808
static const long O5 = 134332456;  // aug_pos     32808
static const long O6 = 134365264;  // new_events  33554432
static const long O7 = 167919696;  // event_len   32768

// ---------------- ws layout (bytes) ----------------
// 0        double surprise[B*S]        262144
// 262144   float  sims[B*MEM]          1048576  -> 1310720
// 1310720  int    bpos[B*S]            131072   -> 1441792
// 1441792  int    nseg[B]
// 1441824  int    idx[B*KT]
// 1442304  float  cval[B*16*10]        2560
// 1444864  int    cidx[B*16*10]        2560     -> 1447424
// 1447424  int    counters[16]         64
// 1572864  double partial[B*S*H]       4194304  -> 5767168  (fused path)
#define WS_NEED_FUSED 5767168UL

#define N4REG 8388608L  // float4 per 128MB region

typedef float __attribute__((ext_vector_type(4))) f4v;

static __device__ __forceinline__ void nt_store4(float4* p, float4 v) {
    f4v t; t.x = v.x; t.y = v.y; t.z = v.z; t.w = v.w;
    __builtin_nontemporal_store(t, (f4v*)p);
}
static __device__ __forceinline__ float4 nt_load4(const float4* p) {
    f4v t = __builtin_nontemporal_load((const f4v*)p);
    float4 v; v.x = t.x; v.y = t.y; v.z = t.z; v.w = t.w;
    return v;
}

// ------------------------------------------------------------------
// Ordered-stream copy (R13) with PLAIN loads/stores everywhere — the exact
// m13 microbenchmark configuration (sequential walk + plain float4 copy,
// 6.29 TB/s). A/B vs R13: only the load/store idiom in regions 0/1/3 changed.
#define CPY_BLOCKS 4096
__global__ __launch_bounds__(256) void copyall_kernel(
        const float4* __restrict__ in0, const float4* __restrict__ q,
        const float4* __restrict__ k4, const float4* __restrict__ v,
        float4* __restrict__ out4, double* __restrict__ partial, int do_part) {
    long gtid = (long)blockIdx.x * 256 + threadIdx.x;
    const long stride = (long)CPY_BLOCKS * 256;  // 1,048,576 f4 = 16 MB
    for (long i = gtid; i < 4 * N4REG; i += stride) {
        int region = (int)(i >> 23);
        long rel = i & (N4REG - 1);
        if (region == 0) {
            out4[(O0 >> 2) + rel] = in0[rel];
        } else if (region == 1) {
            out4[(O1 >> 2) + rel] = q[rel];
        } else if (region == 3) {
            long chunk = rel >> 17;  // (b*H+h), 131072 f4 per slice
            long r = rel & 131071;
            out4[(O3 >> 2) + chunk * 131232L + 160 + r] = v[rel];
        } else {  // region 2: k -> aug_k interior (plain) + surprise partials
            long chunk = rel >> 17;
            long r = rel & 131071;
            float4 cur = k4[rel];
            out4[(O2 >> 2) + chunk * 131232L + 160 + r] = cur;
            if (do_part) {
                int s = (int)(r >> 4);  // 16 f4 per row
                if (s > 0) {
                    float4 pv = k4[rel - 16];
                    double dx = (double)cur.x - (double)pv.x;
                    double dy = (double)cur.y - (double)pv.y;
                    double dz = (double)cur.z - (double)pv.z;
                    double dw = (double)cur.w - (double)pv.w;
                    double acc = dx * dx + dy * dy + dz * dz + dw * dw;
                    acc += __shfl_xor(acc, 1, 64);
                    acc += __shfl_xor(acc, 2, 64);
                    acc += __shfl_xor(acc, 4, 64);
                    acc += __shfl_xor(acc, 8, 64);
                    if ((threadIdx.x & 15) == 0) {
                        int b = (int)(chunk >> 4);
                        int h = (int)(chunk & 15);
                        partial[((long)b * SS + s) * HH + h] = acc;
                    }
                }
            }
        }
    }
}

// sims: standalone, 4096 blocks, full 65536 coverage (unchanged from R13)
#define SIMS_BLOCKS 4096
__global__ __launch_bounds__(256) void sims_kernel(
        const float4* __restrict__ k4, const float4* __restrict__ events4,
        float* __restrict__ sims) {
    __shared__ float4 qls4[BB][256];
    int blk = blockIdx.x;
    int tid = threadIdx.x;
    for (int j = tid; j < BB * 256; j += 256) {
        int b = j >> 8;
        int f4i = j & 255;
        qls4[b][f4i] =
            k4[((long)(b * HH + (f4i >> 4)) * SS + (SS - 1)) * 16 + (f4i & 15)];
    }
    __syncthreads();
    int w = tid >> 6;
    int lane = tid & 63;
    long e0 = (long)blk * 4 + w;
    for (int rr = 0; rr < 4; ++rr) {
        long e = e0 + (long)rr * (4 * SIMS_BLOCKS);
        const float4* er = events4 + e * 256;
        float en = 0.f, d0 = 0.f, d1 = 0.f, d2 = 0.f, d3 = 0.f;
#pragma unroll
        for (int it = 0; it < 4; ++it) {
            int j4 = lane + it * 64;
            float4 ev = nt_load4(er + j4);
            en += ev.x * ev.x + ev.y * ev.y + ev.z * ev.z + ev.w * ev.w;
            float4 q0 = qls4[0][j4];
            d0 += ev.x * q0.x + ev.y * q0.y + ev.z * q0.z + ev.w * q0.w;
            float4 q1 = qls4[1][j4];
            d1 += ev.x * q1.x + ev.y * q1.y + ev.z * q1.z + ev.w * q1.w;
            float4 q2 = qls4[2][j4];
            d2 += ev.x * q2.x + ev.y * q2.y + ev.z * q2.z + ev.w * q2.w;
            float4 q3 = qls4[3][j4];
            d3 += ev.x * q3.x + ev.y * q3.y + ev.z * q3.z + ev.w * q3.w;
        }
        for (int m = 32; m >= 1; m >>= 1) {
            en += __shfl_xor(en, m, 64);
            d0 += __shfl_xor(d0, m, 64);
            d1 += __shfl_xor(d1, m, 64);
            d2 += __shfl_xor(d2, m, 64);
            d3 += __shfl_xor(d3, m, 64);
        }
        if (lane == 0) {
            float enn = fmaxf(sqrtf(en), 1e-8f);
            sims[0 * (long)MEM + e] = d0 / enn;
            sims[1 * (long)MEM + e] = d1 / enn;
            sims[2 * (long)MEM + e] = d2 / enn;
            sims[3 * (long)MEM + e] = d3 / enn;
        }
    }
}

// fallback (small ws): standalone surprise pass reading k directly
__global__ __launch_bounds__(256) void surprise_fallback_kernel(
        const float* __restrict__ k, double* __restrict__ surprise) {
    int wid = (int)(((long)blockIdx.x * blockDim.x + threadIdx.x) >> 6);
    int lane = threadIdx.x & 63;
    if (wid >= BB * SS) return;
    int b = wid >> 13;
    int s = wid & (SS - 1);
    double acc = 0.0;
    if (s > 0) {
        const float* kb = k + (long)b * HH * SS * HDD;
        for (int h = 0; h < HH; ++h) {
            long off = ((long)h * SS + s) * HDD + lane;
            double d = (double)kb[off] - (double)kb[off - HDD];
            acc += d * d;
        }
        for (int m = 32; m >= 1; m >>= 1) acc += __shfl_xor(acc, m, 64);
    }
    if (lane == 0) surprise[wid] = (s == 0) ? 0.0 : sqrt(acc);
}

// ------------------------------------------------------------------
// postfused: one kernel, 120 blocks x 1024 threads, ws spin barriers.
__global__ __launch_bounds__(1024) void postfused_kernel(
        const double* __restrict__ partial, double* __restrict__ surprise,
        int* __restrict__ bpos, int* __restrict__ nseg,
        const float* __restrict__ sims, float* __restrict__ cval,
        int* __restrict__ cidx, int* __restrict__ idxout,
        const float* __restrict__ amask, const void* __restrict__ seqp,
        float* __restrict__ out, int* __restrict__ counters, int fused) {
    __shared__ double sd[1024];
    __shared__ int si[1024];
    __shared__ float lv[256][KT];
    __shared__ int li[256][KT];
    int blk = blockIdx.x;
    int tid = threadIdx.x;

    if (blk < 32) {
        // ---- surprise reduce ----
        if (fused) {
            int t = blk * 1024 + tid;
            int s = t & (SS - 1);
            double acc = 0.0;
            if (s > 0) {
                const double* row = partial + (long)t * HH;
#pragma unroll
                for (int h = 0; h < HH; ++h) acc += row[h];
            }
            surprise[t] = (s == 0) ? 0.0 : sqrt(acc);
        }
        __threadfence();
        __syncthreads();
        if (tid == 0) atomicAdd(&counters[0], 1);
    } else if (blk < 36) {
        // ---- stats + scan (per batch) ----
        if (tid == 0) {
            while (atomicAdd(&counters[0], 0) < 32) __builtin_amdgcn_s_sleep(8);
        }
        __syncthreads();
        __threadfence();
        int b = blk - 32;
        const double* sp = surprise + (long)b * SS;
        double loc[8];
        double sum = 0.0;
        for (int j = 0; j < 8; ++j) { loc[j] = sp[tid * 8 + j]; sum += loc[j]; }
        sd[tid] = sum;
        __syncthreads();
        for (int off = 512; off >= 1; off >>= 1) {
            if (tid < off) sd[tid] += sd[tid + off];
            __syncthreads();
        }
        double mean = sd[0] / SS;
        __syncthreads();
        double vs = 0.0;
        for (int j = 0; j < 8; ++j) { double d = loc[j] - mean; vs += d * d; }
        sd[tid] = vs;
        __syncthreads();
        for (int off = 512; off >= 1; off >>= 1) {
            if (tid < off) sd[tid] += sd[tid + off];
            __syncthreads();
        }
        double thr = mean + 0.5 * sqrt(sd[0] / (SS - 1));
        __syncthreads();
        int bi[8];
        int cnt = 0;
        for (int j = 0; j < 8; ++j) {
            int s = tid * 8 + j;
            bi[j] = (s == SS - 1) || (loc[j] > thr);
            cnt += bi[j];
        }
        si[tid] = cnt;
        __syncthreads();
        for (int off = 1; off < 1024; off <<= 1) {
            int v = 0;
            if (tid >= off) v = si[tid - off];
            __syncthreads();
            si[tid] += v;
            __syncthreads();
        }
        int run = si[tid] - cnt;  // exclusive prefix
        for (int j = 0; j < 8; ++j) {
            if (bi[j]) { bpos[(long)b * SS + run] = tid * 8 + j; ++run; }
        }
        if (tid == 1023) nseg[b] = si[1023];
    } else if (blk < 100) {
        // ---- topk_part (256 active threads) ----
        int g = blk - 36;  // b*16 + part
        int b = g >> 4;
        int part = g & 15;
        if (tid < 256) {
            const float* sb = sims + (long)b * MEM + part * 4096;
            float val[KT];
            int idx[KT];
#pragma unroll
            for (int p = 0; p < KT; ++p) { val[p] = -INFINITY; idx[p] = 0x7fffffff; }
            for (int it = 0; it < 16; ++it) {
                int e = tid + it * 256;
                float v = sb[e];
                if (v > val[KT - 1]) {
#pragma unroll
                    for (int p = KT - 1; p >= 1; --p) {
                        if (v > val[p - 1]) {
                            val[p] = val[p - 1];
                            idx[p] = idx[p - 1];
                        } else {
                            val[p] = v;
                            idx[p] = e;
                            v = -INFINITY;
                        }
                    }
                    if (v != -INFINITY) { val[0] = v; idx[0] = e; }
                }
            }
#pragma unroll
            for (int p = 0; p < KT; ++p) { lv[tid][p] = val[p]; li[tid][p] = idx[p]; }
        }
        for (int off = 128; off >= 1; off >>= 1) {
            __syncthreads();
            if (tid < off) {
                float a_[KT], b_[KT], m_[KT];
                int ai_[KT], bi_[KT], mi_[KT];
#pragma unroll
                for (int p = 0; p < KT; ++p) {
                    a_[p] = lv[tid][p];
                    ai_[p] = li[tid][p];
                    b_[p] = lv[tid + off][p];
                    bi_[p] = li[tid + off][p];
                }
                int pa = 0, pb = 0;
#pragma unroll
                for (int p = 0; p < KT; ++p) {
                    bool ta = (a_[pa] > b_[pb]) ||
                              (a_[pa] == b_[pb] && ai_[pa] < bi_[pb]);
                    if (ta) { m_[p] = a_[pa]; mi_[p] = ai_[pa]; ++pa; }
                    else    { m_[p] = b_[pb]; mi_[p] = bi_[pb]; ++pb; }
                }
#pragma unroll
                for (int p = 0; p < KT; ++p) { lv[tid][p] = m_[p]; li[tid][p] = mi_[p]; }
            }
        }
        __syncthreads();
        if (tid == 0) {
#pragma unroll
            for (int p = 0; p < KT; ++p) {
                cval[g * KT + p] = lv[0][p];
                cidx[g * KT + p] = part * 4096 + li[0][p];
            }
        }
        __threadfence();
        __syncthreads();
        if (tid == 0) atomicAdd(&counters[1], 1);
    } else if (blk < 104) {
        // ---- topk_merge (per batch) ----
        if (tid == 0) {
            while (atomicAdd(&counters[1], 0) < 64) __builtin_amdgcn_s_sleep(8);
        }
        __syncthreads();
        __threadfence();
        int b = blk - 100;
        float mv = -INFINITY;
        int mi = 0x7fffffff;
        if (tid < 160) { mv = cval[b * 160 + tid]; mi = cidx[b * 160 + tid]; }
        if (tid < 256) { lv[tid][0] = mv; li[tid][0] = mi; }
        __syncthreads();
        if (tid == 0) {
            for (int p = 0; p < KT; ++p) {
                float best = -INFINITY;
                int bi = 0x7fffffff;
                int bslot = 0;
                for (int j = 0; j < 160; ++j) {
                    if (lv[j][0] > best || (lv[j][0] == best && li[j][0] < bi)) {
                        best = lv[j][0];
                        bi = li[j][0];
                        bslot = j;
                    }
                }
                idxout[b * KT + p] = bi;
                lv[bslot][0] = -INFINITY;
                li[bslot][0] = 0x7fffffff;
            }
        }
    } else {
        // ---- mask / positions ----
        int iv = ((const int*)seqp)[0];
        int seqlen;
        if (iv > 0 && iv < (1 << 24)) seqlen = iv;
        else seqlen = (int)(((const float*)seqp)[0]);
        int cp = seqlen - 1;
        int n = BB * AUGROWS;
        int i = (blk - 104) * 1024 + tid;
        int stride = 16 * 1024;
        for (; i < n; i += stride) {
            int b = i / AUGROWS;
            int t = i - b * AUGROWS;
            out[O4 + i] = (t < KT) ? 1.0f : amask[(long)b * SS + t - KT];
            out[O5 + i] = (t < KT) ? (float)(cp - KT + t) : (float)(t - KT);
        }
    }
}

// segment means (reads aug_k, cache-hot from plain stores) + zero rows +
// gather fronts
__global__ __launch_bounds__(256) void segtail_kernel(
        const float4* __restrict__ out4c, const int* __restrict__ bpos,
        const int* __restrict__ nseg, const float* __restrict__ events,
        const int* __restrict__ idxin, float* __restrict__ out) {
    int blk = blockIdx.x;
    int tid = threadIdx.x;
    float4* ne4 = (float4*)(out + O6);
    if (blk < BB * SS) {
        int b = blk >> 13;
        int j = blk & (SS - 1);
        int ns = nseg[b];
        float4* row = ne4 + ((long)b * SS + j) * 256;
        if (j >= ns) {
            nt_store4(row + tid, make_float4(0.f, 0.f, 0.f, 0.f));
            if (tid == 0) out[O7 + (long)b * SS + j] = 0.0f;
            return;
        }
        int start = (j == 0) ? 0 : bpos[(long)b * SS + j - 1] + 1;
        int end = bpos[(long)b * SS + j];
        const float4* kb = out4c + (O2 >> 2) +
                           ((long)(b * HH + (tid >> 4)) * AUGROWS + KT) * 16 +
                           (tid & 15);
        double a0 = 0.0, a1 = 0.0, a2 = 0.0, a3 = 0.0;
        for (int s = start; s <= end; ++s) {
            float4 x = kb[(long)s * 16];
            a0 += (double)x.x; a1 += (double)x.y; a2 += (double)x.z; a3 += (double)x.w;
        }
        double inv = 1.0 / (double)(end - start + 1);
        nt_store4(row + tid, make_float4((float)(a0 * inv), (float)(a1 * inv),
                                         (float)(a2 * inv), (float)(a3 * inv)));
        if (tid == 0) out[O7 + (long)b * SS + j] = (float)(end - start + 1);
    } else {
        int g = blk - BB * SS;
        int b = g / KT;
        int t = g % KT;
        int ev = idxin[b * KT + t];
        for (int c = 0; c < 4; ++c) {
            int j = tid + c * 256;
            float vv = events[(long)ev * DD + j];
            int h = j >> 6;
            int d = j & 63;
            long dst = (((long)b * HH + h) * AUGROWS + t) * HDD + d;
            out[O2 + dst] = vv;
            out[O3 + dst] = vv;
        }
    }
}

extern "C" void kernel_launch(void* const* d_in, const int* in_sizes, int n_in,
                              void* d_out, int out_size, void* d_ws, size_t ws_size,
                              hipStream_t stream) {
    const float* in_inputs = (const float*)d_in[0];
    const float* in_q = (const float*)d_in[1];
    const float* in_k = (const float*)d_in[2];
    const float* in_v = (const float*)d_in[3];
    const float* in_amask = (const float*)d_in[4];
    const float* in_events = (const float*)d_in[5];
    const void* in_seq = d_in[6];
    float* out = (float*)d_out;

    char* ws = (char*)d_ws;
    double* surprise = (double*)ws;
    float* sims = (float*)(ws + 262144);
    int* bpos = (int*)(ws + 1310720);
    int* nseg = (int*)(ws + 1441792);
    int* idxw = (int*)(ws + 1441824);
    float* cval = (float*)(ws + 1442304);
    int* cidx = (int*)(ws + 1444864);
    int* counters = (int*)(ws + 1447424);
    double* partial = (double*)(ws + 1572864);

    const int fused = (ws_size >= WS_NEED_FUSED) ? 1 : 0;

    hipMemsetAsync(counters, 0, 64, stream);
    sims_kernel<<<SIMS_BLOCKS, 256, 0, stream>>>(
        (const float4*)in_k, (const float4*)in_events, sims);
    copyall_kernel<<<CPY_BLOCKS, 256, 0, stream>>>(
        (const float4*)in_inputs, (const float4*)in_q, (const float4*)in_k,
        (const float4*)in_v, (float4*)out, partial, fused);
    if (!fused)
        surprise_fallback_kernel<<<8192, 256, 0, stream>>>(in_k, surprise);
    postfused_kernel<<<120, 1024, 0, stream>>>(
        partial, surprise, bpos, nseg, sims, cval, cidx, idxw, in_amask,
        in_seq, out, counters, fused);
    segtail_kernel<<<BB * SS + BB * KT, 256, 0, stream>>>(
        (const float4*)out, bpos, nseg, in_events, idxw, out);
}

// Round 15
// 430.804 us; speedup vs baseline: 1.1240x; 1.1240x over previous
//
#include <hip/hip_runtime.h>
#include <math.h>

#define BB 4
#define HH 16
#define SS 8192
#define HDD 64
#define DD 1024
#define MEM 65536
#define KT 10
#define AUGROWS (SS + KT)

// ---------------- output offsets (floats) ----------------
static const long O0 = 0;          // inputs      33554432
static const long O1 = 33554432;   // q           33554432
static const long O2 = 67108864;   // aug_k       33595392 (B,H,S+KT,HD)
static const long O3 = 100704256;  // aug_v       33595392
static const long O4 = 134299648;  // aug_mask    32808
static const long O5 = 134332456;  // aug_pos     32808
static const long O6 = 134365264;  // new_events  33554432
static const long O7 = 167919696;  // event_len   32768

// ---------------- ws layout (bytes) ----------------
// 0        double surprise[B*S]        262144
// 262144   float  sims[B*MEM]          1048576  -> 1310720
// 1310720  int    bpos[B*S]            131072   -> 1441792
// 1441792  int    nseg[B]
// 1441824  int    idx[B*KT]
// 1442304  float  cval[B*16*10]        2560
// 1444864  int    cidx[B*16*10]        2560     -> 1447424
// 1447424  int    counters[16]         64
// 1572864  double partial[B*S*H]       4194304  -> 5767168  (fused path)
#define WS_NEED_FUSED 5767168UL

#define N4REG 8388608L  // float4 per 128MB region

typedef float __attribute__((ext_vector_type(4))) f4v;

static __device__ __forceinline__ void nt_store4(float4* p, float4 v) {
    f4v t; t.x = v.x; t.y = v.y; t.z = v.z; t.w = v.w;
    __builtin_nontemporal_store(t, (f4v*)p);
}
static __device__ __forceinline__ float4 nt_load4(const float4* p) {
    f4v t = __builtin_nontemporal_load((const f4v*)p);
    float4 v; v.x = t.x; v.y = t.y; v.z = t.z; v.w = t.w;
    return v;
}

// ------------------------------------------------------------------
// Best-known structure (R7 = 431 us): concurrent bands, NT load/store on
// stream-once data, plain stores for aug_k (read back by segtail).
#define COPY_BLOCKS 4096
#define SIMS_BLOCKS 4096
__global__ __launch_bounds__(256) void bigfused_kernel(
        const float4* __restrict__ in0, const float4* __restrict__ q,
        const float4* __restrict__ k4, const float4* __restrict__ v,
        const float4* __restrict__ events4, float4* __restrict__ out4,
        double* __restrict__ partial, float* __restrict__ sims, int do_part) {
    __shared__ float4 qls4[BB][256];
    int blk = blockIdx.x;
    int tid = threadIdx.x;
    if (blk < COPY_BLOCKS) {
        int band = blk >> 10;
        long i = ((long)(blk & 1023)) * 256 + tid;
        const long bstride = 1024L * 256;
        if (band == 0) {
            for (; i < N4REG; i += bstride)
                nt_store4(out4 + (O0 >> 2) + i, nt_load4(in0 + i));
        } else if (band == 1) {
            for (; i < N4REG; i += bstride)
                nt_store4(out4 + (O1 >> 2) + i, nt_load4(q + i));
        } else if (band == 3) {
            for (; i < N4REG; i += bstride) {
                long chunk = i >> 17;  // (b*H+h), 131072 float4 per slice
                long r = i & 131071;
                nt_store4(out4 + (O3 >> 2) + chunk * 131232L + 160 + r,
                          nt_load4(v + i));
            }
        } else {  // band 2: k interior copy (plain stores) + surprise partials
            for (; i < N4REG; i += bstride) {
                long chunk = i >> 17;
                long r = i & 131071;
                float4 cur = k4[i];
                out4[(O2 >> 2) + chunk * 131232L + 160 + r] = cur;
                if (do_part) {
                    int s = (int)(r >> 4);  // 16 float4 per row
                    if (s > 0) {
                        float4 pv = k4[i - 16];
                        double dx = (double)cur.x - (double)pv.x;
                        double dy = (double)cur.y - (double)pv.y;
                        double dz = (double)cur.z - (double)pv.z;
                        double dw = (double)cur.w - (double)pv.w;
                        double acc = dx * dx + dy * dy + dz * dz + dw * dw;
                        acc += __shfl_xor(acc, 1, 64);
                        acc += __shfl_xor(acc, 2, 64);
                        acc += __shfl_xor(acc, 4, 64);
                        acc += __shfl_xor(acc, 8, 64);
                        if ((tid & 15) == 0) {
                            int b = (int)(chunk >> 4);
                            int h = (int)(chunk & 15);
                            partial[((long)b * SS + s) * HH + h] = acc;
                        }
                    }
                }
            }
        }
    } else {
        // sims: 4 rows per wave (stride 16384), full 65536 coverage
        for (int j = tid; j < BB * 256; j += 256) {
            int b = j >> 8;
            int f4i = j & 255;
            qls4[b][f4i] =
                k4[((long)(b * HH + (f4i >> 4)) * SS + (SS - 1)) * 16 + (f4i & 15)];
        }
        __syncthreads();
        int w = tid >> 6;
        int lane = tid & 63;
        long e0 = (long)(blk - COPY_BLOCKS) * 4 + w;
        for (int rr = 0; rr < 4; ++rr) {
            long e = e0 + (long)rr * (4 * SIMS_BLOCKS);
            const float4* er = events4 + e * 256;
            float en = 0.f, d0 = 0.f, d1 = 0.f, d2 = 0.f, d3 = 0.f;
#pragma unroll
            for (int it = 0; it < 4; ++it) {
                int j4 = lane + it * 64;
                float4 ev = nt_load4(er + j4);
                en += ev.x * ev.x + ev.y * ev.y + ev.z * ev.z + ev.w * ev.w;
                float4 q0 = qls4[0][j4];
                d0 += ev.x * q0.x + ev.y * q0.y + ev.z * q0.z + ev.w * q0.w;
                float4 q1 = qls4[1][j4];
                d1 += ev.x * q1.x + ev.y * q1.y + ev.z * q1.z + ev.w * q1.w;
                float4 q2 = qls4[2][j4];
                d2 += ev.x * q2.x + ev.y * q2.y + ev.z * q2.z + ev.w * q2.w;
                float4 q3 = qls4[3][j4];
                d3 += ev.x * q3.x + ev.y * q3.y + ev.z * q3.z + ev.w * q3.w;
            }
            for (int m = 32; m >= 1; m >>= 1) {
                en += __shfl_xor(en, m, 64);
                d0 += __shfl_xor(d0, m, 64);
                d1 += __shfl_xor(d1, m, 64);
                d2 += __shfl_xor(d2, m, 64);
                d3 += __shfl_xor(d3, m, 64);
            }
            if (lane == 0) {
                float enn = fmaxf(sqrtf(en), 1e-8f);
                sims[0 * (long)MEM + e] = d0 / enn;
                sims[1 * (long)MEM + e] = d1 / enn;
                sims[2 * (long)MEM + e] = d2 / enn;
                sims[3 * (long)MEM + e] = d3 / enn;
            }
        }
    }
}

// fallback (small ws): standalone surprise pass reading k directly
__global__ __launch_bounds__(256) void surprise_fallback_kernel(
        const float* __restrict__ k, double* __restrict__ surprise) {
    int wid = (int)(((long)blockIdx.x * blockDim.x + threadIdx.x) >> 6);
    int lane = threadIdx.x & 63;
    if (wid >= BB * SS) return;
    int b = wid >> 13;
    int s = wid & (SS - 1);
    double acc = 0.0;
    if (s > 0) {
        const float* kb = k + (long)b * HH * SS * HDD;
        for (int h = 0; h < HH; ++h) {
            long off = ((long)h * SS + s) * HDD + lane;
            double d = (double)kb[off] - (double)kb[off - HDD];
            acc += d * d;
        }
        for (int m = 32; m >= 1; m >>= 1) acc += __shfl_xor(acc, m, 64);
    }
    if (lane == 0) surprise[wid] = (s == 0) ? 0.0 : sqrt(acc);
}

// ------------------------------------------------------------------
// postfused: one kernel, 120 blocks x 1024 threads, ws spin barriers.
//   [0,32)    reduce partials -> surprise            -> signal c0
//   [32,36)   stats+scan per batch (spin c0==32)
//   [36,100)  topk_part (independent of c0)          -> signal c1
//   [100,104) topk_merge (spin c1==64)
//   [104,120) mask/positions (independent)
__global__ __launch_bounds__(1024) void postfused_kernel(
        const double* __restrict__ partial, double* __restrict__ surprise,
        int* __restrict__ bpos, int* __restrict__ nseg,
        const float* __restrict__ sims, float* __restrict__ cval,
        int* __restrict__ cidx, int* __restrict__ idxout,
        const float* __restrict__ amask, const void* __restrict__ seqp,
        float* __restrict__ out, int* __restrict__ counters, int fused) {
    __shared__ double sd[1024];
    __shared__ int si[1024];
    __shared__ float lv[256][KT];
    __shared__ int li[256][KT];
    int blk = blockIdx.x;
    int tid = threadIdx.x;

    if (blk < 32) {
        // ---- surprise reduce ----
        if (fused) {
            int t = blk * 1024 + tid;
            int s = t & (SS - 1);
            double acc = 0.0;
            if (s > 0) {
                const double* row = partial + (long)t * HH;
#pragma unroll
                for (int h = 0; h < HH; ++h) acc += row[h];
            }
            surprise[t] = (s == 0) ? 0.0 : sqrt(acc);
        }
        __threadfence();
        __syncthreads();
        if (tid == 0) atomicAdd(&counters[0], 1);
    } else if (blk < 36) {
        // ---- stats + scan (per batch) ----
        if (tid == 0) {
            while (atomicAdd(&counters[0], 0) < 32) __builtin_amdgcn_s_sleep(8);
        }
        __syncthreads();
        __threadfence();
        int b = blk - 32;
        const double* sp = surprise + (long)b * SS;
        double loc[8];
        double sum = 0.0;
        for (int j = 0; j < 8; ++j) { loc[j] = sp[tid * 8 + j]; sum += loc[j]; }
        sd[tid] = sum;
        __syncthreads();
        for (int off = 512; off >= 1; off >>= 1) {
            if (tid < off) sd[tid] += sd[tid + off];
            __syncthreads();
        }
        double mean = sd[0] / SS;
        __syncthreads();
        double vs = 0.0;
        for (int j = 0; j < 8; ++j) { double d = loc[j] - mean; vs += d * d; }
        sd[tid] = vs;
        __syncthreads();
        for (int off = 512; off >= 1; off >>= 1) {
            if (tid < off) sd[tid] += sd[tid + off];
            __syncthreads();
        }
        double thr = mean + 0.5 * sqrt(sd[0] / (SS - 1));
        __syncthreads();
        int bi[8];
        int cnt = 0;
        for (int j = 0; j < 8; ++j) {
            int s = tid * 8 + j;
            bi[j] = (s == SS - 1) || (loc[j] > thr);
            cnt += bi[j];
        }
        si[tid] = cnt;
        __syncthreads();
        for (int off = 1; off < 1024; off <<= 1) {
            int v = 0;
            if (tid >= off) v = si[tid - off];
            __syncthreads();
            si[tid] += v;
            __syncthreads();
        }
        int run = si[tid] - cnt;  // exclusive prefix
        for (int j = 0; j < 8; ++j) {
            if (bi[j]) { bpos[(long)b * SS + run] = tid * 8 + j; ++run; }
        }
        if (tid == 1023) nseg[b] = si[1023];
    } else if (blk < 100) {
        // ---- topk_part (256 active threads) ----
        int g = blk - 36;  // b*16 + part
        int b = g >> 4;
        int part = g & 15;
        if (tid < 256) {
            const float* sb = sims + (long)b * MEM + part * 4096;
            float val[KT];
            int idx[KT];
#pragma unroll
            for (int p = 0; p < KT; ++p) { val[p] = -INFINITY; idx[p] = 0x7fffffff; }
            for (int it = 0; it < 16; ++it) {
                int e = tid + it * 256;
                float v = sb[e];
                if (v > val[KT - 1]) {
#pragma unroll
                    for (int p = KT - 1; p >= 1; --p) {
                        if (v > val[p - 1]) {
                            val[p] = val[p - 1];
                            idx[p] = idx[p - 1];
                        } else {
                            val[p] = v;
                            idx[p] = e;
                            v = -INFINITY;
                        }
                    }
                    if (v != -INFINITY) { val[0] = v; idx[0] = e; }
                }
            }
#pragma unroll
            for (int p = 0; p < KT; ++p) { lv[tid][p] = val[p]; li[tid][p] = idx[p]; }
        }
        for (int off = 128; off >= 1; off >>= 1) {
            __syncthreads();
            if (tid < off) {
                float a_[KT], b_[KT], m_[KT];
                int ai_[KT], bi_[KT], mi_[KT];
#pragma unroll
                for (int p = 0; p < KT; ++p) {
                    a_[p] = lv[tid][p];
                    ai_[p] = li[tid][p];
                    b_[p] = lv[tid + off][p];
                    bi_[p] = li[tid + off][p];
                }
                int pa = 0, pb = 0;
#pragma unroll
                for (int p = 0; p < KT; ++p) {
                    bool ta = (a_[pa] > b_[pb]) ||
                              (a_[pa] == b_[pb] && ai_[pa] < bi_[pb]);
                    if (ta) { m_[p] = a_[pa]; mi_[p] = ai_[pa]; ++pa; }
                    else    { m_[p] = b_[pb]; mi_[p] = bi_[pb]; ++pb; }
                }
#pragma unroll
                for (int p = 0; p < KT; ++p) { lv[tid][p] = m_[p]; li[tid][p] = mi_[p]; }
            }
        }
        __syncthreads();
        if (tid == 0) {
#pragma unroll
            for (int p = 0; p < KT; ++p) {
                cval[g * KT + p] = lv[0][p];
                cidx[g * KT + p] = part * 4096 + li[0][p];
            }
        }
        __threadfence();
        __syncthreads();
        if (tid == 0) atomicAdd(&counters[1], 1);
    } else if (blk < 104) {
        // ---- topk_merge (per batch) ----
        if (tid == 0) {
            while (atomicAdd(&counters[1], 0) < 64) __builtin_amdgcn_s_sleep(8);
        }
        __syncthreads();
        __threadfence();
        int b = blk - 100;
        float mv = -INFINITY;
        int mi = 0x7fffffff;
        if (tid < 160) { mv = cval[b * 160 + tid]; mi = cidx[b * 160 + tid]; }
        if (tid < 256) { lv[tid][0] = mv; li[tid][0] = mi; }
        __syncthreads();
        if (tid == 0) {
            for (int p = 0; p < KT; ++p) {
                float best = -INFINITY;
                int bi = 0x7fffffff;
                int bslot = 0;
                for (int j = 0; j < 160; ++j) {
                    if (lv[j][0] > best || (lv[j][0] == best && li[j][0] < bi)) {
                        best = lv[j][0];
                        bi = li[j][0];
                        bslot = j;
                    }
                }
                idxout[b * KT + p] = bi;
                lv[bslot][0] = -INFINITY;
                li[bslot][0] = 0x7fffffff;
            }
        }
    } else {
        // ---- mask / positions ----
        int iv = ((const int*)seqp)[0];
        int seqlen;
        if (iv > 0 && iv < (1 << 24)) seqlen = iv;
        else seqlen = (int)(((const float*)seqp)[0]);
        int cp = seqlen - 1;
        int n = BB * AUGROWS;
        int i = (blk - 104) * 1024 + tid;
        int stride = 16 * 1024;
        for (; i < n; i += stride) {
            int b = i / AUGROWS;
            int t = i - b * AUGROWS;
            out[O4 + i] = (t < KT) ? 1.0f : amask[(long)b * SS + t - KT];
            out[O5 + i] = (t < KT) ? (float)(cp - KT + t) : (float)(t - KT);
        }
    }
}

// segment means (reads aug_k, L3-hot) + zero rows + gather fronts
__global__ __launch_bounds__(256) void segtail_kernel(
        const float4* __restrict__ out4c, const int* __restrict__ bpos,
        const int* __restrict__ nseg, const float* __restrict__ events,
        const int* __restrict__ idxin, float* __restrict__ out) {
    int blk = blockIdx.x;
    int tid = threadIdx.x;
    float4* ne4 = (float4*)(out + O6);
    if (blk < BB * SS) {
        int b = blk >> 13;
        int j = blk & (SS - 1);
        int ns = nseg[b];
        float4* row = ne4 + ((long)b * SS + j) * 256;
        if (j >= ns) {
            nt_store4(row + tid, make_float4(0.f, 0.f, 0.f, 0.f));
            if (tid == 0) out[O7 + (long)b * SS + j] = 0.0f;
            return;
        }
        int start = (j == 0) ? 0 : bpos[(long)b * SS + j - 1] + 1;
        int end = bpos[(long)b * SS + j];
        const float4* kb = out4c + (O2 >> 2) +
                           ((long)(b * HH + (tid >> 4)) * AUGROWS + KT) * 16 +
                           (tid & 15);
        double a0 = 0.0, a1 = 0.0, a2 = 0.0, a3 = 0.0;
        for (int s = start; s <= end; ++s) {
            float4 x = kb[(long)s * 16];
            a0 += (double)x.x; a1 += (double)x.y; a2 += (double)x.z; a3 += (double)x.w;
        }
        double inv = 1.0 / (double)(end - start + 1);
        nt_store4(row + tid, make_float4((float)(a0 * inv), (float)(a1 * inv),
                                         (float)(a2 * inv), (float)(a3 * inv)));
        if (tid == 0) out[O7 + (long)b * SS + j] = (float)(end - start + 1);
    } else {
        int g = blk - BB * SS;
        int b = g / KT;
        int t = g % KT;
        int ev = idxin[b * KT + t];
        for (int c = 0; c < 4; ++c) {
            int j = tid + c * 256;
            float vv = events[(long)ev * DD + j];
            int h = j >> 6;
            int d = j & 63;
            long dst = (((long)b * HH + h) * AUGROWS + t) * HDD + d;
            out[O2 + dst] = vv;
            out[O3 + dst] = vv;
        }
    }
}

extern "C" void kernel_launch(void* const* d_in, const int* in_sizes, int n_in,
                              void* d_out, int out_size, void* d_ws, size_t ws_size,
                              hipStream_t stream) {
    const float* in_inputs = (const float*)d_in[0];
    const float* in_q = (const float*)d_in[1];
    const float* in_k = (const float*)d_in[2];
    const float* in_v = (const float*)d_in[3];
    const float* in_amask = (const float*)d_in[4];
    const float* in_events = (const float*)d_in[5];
    const void* in_seq = d_in[6];
    float* out = (float*)d_out;

    char* ws = (char*)d_ws;
    double* surprise = (double*)ws;
    float* sims = (float*)(ws + 262144);
    int* bpos = (int*)(ws + 1310720);
    int* nseg = (int*)(ws + 1441792);
    int* idxw = (int*)(ws + 1441824);
    float* cval = (float*)(ws + 1442304);
    int* cidx = (int*)(ws + 1444864);
    int* counters = (int*)(ws + 1447424);
    double* partial = (double*)(ws + 1572864);

    const int fused = (ws_size >= WS_NEED_FUSED) ? 1 : 0;

    hipMemsetAsync(counters, 0, 64, stream);
    bigfused_kernel<<<COPY_BLOCKS + SIMS_BLOCKS, 256, 0, stream>>>(
        (const float4*)in_inputs, (const float4*)in_q, (const float4*)in_k,
        (const float4*)in_v, (const float4*)in_events, (float4*)out, partial,
        sims, fused);
    if (!fused)
        surprise_fallback_kernel<<<8192, 256, 0, stream>>>(in_k, surprise);
    postfused_kernel<<<120, 1024, 0, stream>>>(
        partial, surprise, bpos, nseg, sims, cval, cidx, idxw, in_amask,
        in_seq, out, counters, fused);
    segtail_kernel<<<BB * SS + BB * KT, 256, 0, stream>>>(
        (const float4*)out, bpos, nseg, in_events, idxw, out);
}